// Round 1
// baseline (2392.802 us; speedup 1.0000x reference)
//
#include <hip/hip_runtime.h>
#include <math.h>

// Hungarian (reference-exact degenerate JV) + MSE loss.
// pred/target: (B=32, N=256, 2) float32. Output: scalar float32 mean((p - matched_t)^2).
//
// NOTE: the Python reference's _lap copies minv/way and never writes them back,
// so minv==inf and way==0 throughout. Effective per-row dynamics (which we
// replicate EXACTLY, in float64 duals like the reference):
//   p[0]=i; j0=0
//   loop: used[j0]=1; i0=p[j0];
//         j1 = argmin_{j free} ( (f64)dist_f32(i0-1, j-1) - u[i0] - v[j] )   (first-index ties)
//         delta = that min; for used j: u[p[j]] += delta, v[j] -= delta
//         j0=j1; if p[j0]==0 break
//   p[j0] = i            (augmentation collapses because way==0)

#define N 256
#define NB1 257

__global__ __launch_bounds__(64) void hung_kernel(const float* __restrict__ pred,
                                                  const float* __restrict__ target,
                                                  double* __restrict__ partial) {
  const int b = blockIdx.x;
  const int lane = threadIdx.x;  // 0..63, single wave per block

  __shared__ float px[N], py[N], tx[N], ty[N];
  __shared__ double u[NB1], v[NB1];
  __shared__ int pcol[NB1];   // pcol[j] = row assigned to column j (1-indexed), 0 = free
  __shared__ int used[NB1];

  const float2* predv = (const float2*)pred + (size_t)b * N;
  const float2* targv = (const float2*)target + (size_t)b * N;
#pragma unroll
  for (int k = 0; k < 4; ++k) {
    int idx = lane + 64 * k;
    float2 pp = predv[idx];
    px[idx] = pp.x; py[idx] = pp.y;
    float2 tt = targv[idx];
    tx[idx] = tt.x; ty[idx] = tt.y;
  }
#pragma unroll
  for (int k = 0; k < 5; ++k) {
    int j = lane + 64 * k;
    if (j < NB1) { u[j] = 0.0; v[j] = 0.0; pcol[j] = 0; }
  }
  __syncthreads();

  for (int i = 1; i <= N; ++i) {
    pcol[0] = i;  // wave-uniform same-value write
#pragma unroll
    for (int k = 0; k < 5; ++k) {
      int j = lane + 64 * k;
      if (j < NB1) used[j] = 0;
    }
    __syncthreads();

    int j0 = 0;
    while (true) {
      used[j0] = 1;  // wave-uniform same-value write
      __syncthreads();

      const int i0 = pcol[j0];
      const double ui0 = u[i0];
      const float pxi = px[i0 - 1];
      const float pyi = py[i0 - 1];

      // parallel scan: each lane owns columns j = 1+lane+64k
      double bestd = __builtin_huge_val();
      int bestj = 0;
#pragma unroll
      for (int k = 0; k < 4; ++k) {
        int j = 1 + lane + 64 * k;
        if (!used[j]) {
          float dx = pxi - tx[j - 1];
          float dy = pyi - ty[j - 1];
          float c = sqrtf(dx * dx + dy * dy);
          double cur = (double)c - ui0 - v[j];
          if (cur < bestd) { bestd = cur; bestj = j; }  // strict < + ascending j => first-index ties
        }
      }
      // wave argmin reduction, tie-break on smaller j (np.argmin first-index)
#pragma unroll
      for (int off = 1; off < 64; off <<= 1) {
        double od = __shfl_xor(bestd, off);
        int oj = __shfl_xor(bestj, off);
        if (od < bestd || (od == bestd && oj < bestj)) { bestd = od; bestj = oj; }
      }
      const double delta = bestd;
      const int j1 = bestj;

      __syncthreads();  // all reads of u/v done before dual update
#pragma unroll
      for (int k = 0; k < 5; ++k) {
        int j = lane + 64 * k;
        if (j < NB1 && used[j]) {
          u[pcol[j]] += delta;  // distinct pcol[j] across used j -> no conflicts
          v[j] -= delta;
        }
      }
      j0 = j1;
      __syncthreads();
      if (pcol[j0] == 0) break;
    }
    pcol[j0] = i;  // wave-uniform same-value write
    __syncthreads();
  }

  // partial MSE: for column j (1..N): row r=pcol[j]-1 matched to col c=j-1
  double s = 0.0;
#pragma unroll
  for (int k = 0; k < 4; ++k) {
    int j = 1 + lane + 64 * k;
    int r = pcol[j] - 1;
    int c = j - 1;
    double dx = (double)px[r] - (double)tx[c];
    double dy = (double)py[r] - (double)ty[c];
    s += dx * dx + dy * dy;
  }
#pragma unroll
  for (int off = 1; off < 64; off <<= 1) s += __shfl_xor(s, off);
  if (lane == 0) partial[b] = s;
}

__global__ __launch_bounds__(64) void reduce_kernel(const double* __restrict__ partial,
                                                    float* __restrict__ out, int B) {
  double s = 0.0;
  for (int i = threadIdx.x; i < B; i += 64) s += partial[i];
#pragma unroll
  for (int off = 1; off < 64; off <<= 1) s += __shfl_xor(s, off);
  if (threadIdx.x == 0) out[0] = (float)(s / (double)(B * N * 2));
}

extern "C" void kernel_launch(void* const* d_in, const int* in_sizes, int n_in,
                              void* d_out, int out_size, void* d_ws, size_t ws_size,
                              hipStream_t stream) {
  const float* pred = (const float*)d_in[0];
  const float* target = (const float*)d_in[1];
  float* out = (float*)d_out;
  double* partial = (double*)d_ws;

  const int B = in_sizes[0] / (N * 2);  // 32

  hipLaunchKernelGGL(hung_kernel, dim3(B), dim3(64), 0, stream, pred, target, partial);
  hipLaunchKernelGGL(reduce_kernel, dim3(1), dim3(64), 0, stream, partial, out, B);
}

// Round 4
// 1830.230 us; speedup vs baseline: 1.3074x; 1.3074x over previous
//
#include <hip/hip_runtime.h>
#include <math.h>

// Hungarian (reference-exact degenerate JV) + MSE.
// Rebuilt from the round-1 bit-exact baseline. Kept EXACTLY as round 1:
//   * u, used, pcol live in LDS; u[i0] read LIVE each step (no caching);
//   * scan expression ((double)c - ui0) - v  (left-assoc, strict FP);
//   * per-step updates: for used j: u[pcol[j]] += delta (LDS RMW), v[j] -= delta;
//   * argmin = first-index (np.argmin) over free columns.
// Changed (each provably value-preserving):
//   * tx/ty + row coords in registers (READ-ONLY data; readlane fetch);
//   * v[j] in owner-lane registers (owner-only access; update mask read live
//     from LDS used[] as in round 1 -> identical FP sequence by induction);
//   * used[] read once per step, reused for scan+update (values identical:
//     used[] only written at step top);
//   * value-only shfl_xor min butterfly; argmin j via 4 ballots + ffs
//     (j = 1+lane+64k is k-major => ballot order = ascending j = first-index);
//     delta re-fetched from argmin lane via readlane (bit-exact incl. +/-0);
//   * 1 real __syncthreads per step (was 3) + compiler-only wave_barriers
//     (single-wave block: per-wave LDS ops are in program order; all
//     cross-lane deps are same-array so the compiler orders them).

#define N 256

__device__ __forceinline__ int f2i(float x) { union { float f; int i; } u; u.f = x; return u.i; }
__device__ __forceinline__ float i2f(int x) { union { float f; int i; } u; u.i = x; return u.f; }
__device__ __forceinline__ double mkd(int lo, int hi) {
  union { unsigned long long u; double d; } w;
  w.u = (((unsigned long long)(unsigned)hi) << 32) | (unsigned)lo;
  return w.d;
}
__device__ __forceinline__ int dlo(double d) { union { double d; unsigned long long u; } w; w.d = d; return (int)(unsigned)w.u; }
__device__ __forceinline__ int dhi(double d) { union { double d; unsigned long long u; } w; w.d = d; return (int)(unsigned)(w.u >> 32); }

__global__ __launch_bounds__(64) void hung_kernel(const float* __restrict__ pred,
                                                  const float* __restrict__ target,
                                                  double* __restrict__ partial) {
  const int b = blockIdx.x;
  const int lane = threadIdx.x;  // single wave per block

  __shared__ float spx[N], spy[N];   // pred coords for final scattered MSE gather
  __shared__ double u_lds[N + 1];    // row duals (LIVE, like round 1)
  __shared__ int pcol[N + 1];        // column -> assigned row (1-indexed), 0 = free
  __shared__ int used[N + 1];        // per-row path marks

  // Read-only per-lane data: columns j-1 = lane+64k; rows r-1 = lane+64k.
  float tx[4], ty[4], rpx[4], rpy[4];
  double v[4];  // column duals, owner-lane only

  const float2* pv = (const float2*)pred + (size_t)b * N;
  const float2* tv = (const float2*)target + (size_t)b * N;
#pragma unroll
  for (int k = 0; k < 4; ++k) {
    int idx = lane + 64 * k;
    float2 pp = pv[idx];
    rpx[k] = pp.x; rpy[k] = pp.y;
    spx[idx] = pp.x; spy[idx] = pp.y;
    float2 tt = tv[idx];
    tx[k] = tt.x; ty[k] = tt.y;
    v[k] = 0.0;
  }
#pragma unroll
  for (int k = 0; k < 5; ++k) {
    int j = lane + 64 * k;
    if (j < N + 1) { u_lds[j] = 0.0; pcol[j] = 0; }
  }
  __syncthreads();

  for (int i = 1; i <= N; ++i) {
    pcol[0] = i;  // wave-uniform same-value store
#pragma unroll
    for (int k = 0; k < 5; ++k) {
      int j = lane + 64 * k;
      if (j < N + 1) used[j] = 0;
    }
    __syncthreads();

    int j0 = 0;
    while (true) {
      used[j0] = 1;  // wave-uniform same-value store
      __builtin_amdgcn_wave_barrier();

      const int i0 = pcol[j0];           // LDS read (uniform addr -> broadcast)
      const double ui0 = u_lds[i0];      // LIVE dual read (round-1 semantics)
      const int rl = (i0 - 1) & 63, rs = (i0 - 1) >> 6;
      const float pxi = i2f(__builtin_amdgcn_readlane(
          rs == 0 ? f2i(rpx[0]) : rs == 1 ? f2i(rpx[1]) : rs == 2 ? f2i(rpx[2]) : f2i(rpx[3]), rl));
      const float pyi = i2f(__builtin_amdgcn_readlane(
          rs == 0 ? f2i(rpy[0]) : rs == 1 ? f2i(rpy[1]) : rs == 2 ? f2i(rpy[2]) : f2i(rpy[3]), rl));

      // ---- read marks once (used[] only written at step top; reuse for update)
      int uj[4];
#pragma unroll
      for (int k = 0; k < 4; ++k) uj[k] = used[1 + lane + 64 * k];

      // ---- scan my free columns, retain m[k] for delta re-fetch
      double m[4];
      double bm = __builtin_huge_val();
#pragma unroll
      for (int k = 0; k < 4; ++k) {
        double mk = __builtin_huge_val();
        if (!uj[k]) {
          float dx = pxi - tx[k];
          float dy = pyi - ty[k];
          float c = sqrtf(dx * dx + dy * dy);
          mk = ((double)c - ui0) - v[k];  // reference rounding order
        }
        m[k] = mk;
        if (mk < bm) bm = mk;
      }

      // ---- value-only min butterfly (proven shfl path)
#pragma unroll
      for (int off = 1; off < 64; off <<= 1) {
        double od = __shfl_xor(bm, off);
        if (od < bm) bm = od;
      }

      // ---- argmin j (first-index): ballots in ascending-k order == ascending j
      unsigned long long b0 = __ballot(m[0] == bm);
      unsigned long long b1 = __ballot(m[1] == bm);
      unsigned long long b2 = __ballot(m[2] == bm);
      unsigned long long b3 = __ballot(m[3] == bm);
      const int ks = b0 ? 0 : (b1 ? 1 : (b2 ? 2 : 3));
      const unsigned long long bb = b0 ? b0 : (b1 ? b1 : (b2 ? b2 : b3));
      const int ls = __ffsll(bb) - 1;
      const int j1 = 1 + ls + 64 * ks;
      // delta = m value AT the argmin (bit-exact, incl. signed-zero cases)
      const int msl = ks == 0 ? dlo(m[0]) : ks == 1 ? dlo(m[1]) : ks == 2 ? dlo(m[2]) : dlo(m[3]);
      const int msh = ks == 0 ? dhi(m[0]) : ks == 1 ? dhi(m[1]) : ks == 2 ? dhi(m[2]) : dhi(m[3]);
      const double delta = mkd(__builtin_amdgcn_readlane(msl, ls),
                               __builtin_amdgcn_readlane(msh, ls));

      __builtin_amdgcn_wave_barrier();
      // ---- dual update (round-1 semantics: LDS u RMW at distinct addresses)
#pragma unroll
      for (int k = 0; k < 4; ++k) {
        if (uj[k]) {
          int r = pcol[1 + lane + 64 * k];  // LIVE pcol read
          u_lds[r] += delta;
          v[k] -= delta;
        }
      }
      if (lane == 0) u_lds[i] += delta;  // virtual column 0: pcol[0] == i

      j0 = j1;
      __syncthreads();  // writes -> next-step reads (one real barrier per step)
      if (pcol[j0] == 0) break;
    }

    pcol[j0] = i;  // augment (way==0 => single write); wave-uniform store
    __syncthreads();
  }

  // ---- partial MSE: column j matched to row pcol[j]-1
  double s = 0.0;
#pragma unroll
  for (int k = 0; k < 4; ++k) {
    int j = 1 + lane + 64 * k;
    int r = pcol[j] - 1;
    double dx = (double)spx[r] - (double)tx[k];
    double dy = (double)spy[r] - (double)ty[k];
    s += dx * dx + dy * dy;
  }
#pragma unroll
  for (int off = 1; off < 64; off <<= 1) s += __shfl_xor(s, off);
  if (lane == 0) partial[b] = s;
}

__global__ __launch_bounds__(64) void reduce_kernel(const double* __restrict__ partial,
                                                    float* __restrict__ out, int B) {
  double s = 0.0;
  for (int i = threadIdx.x; i < B; i += 64) s += partial[i];
#pragma unroll
  for (int off = 1; off < 64; off <<= 1) s += __shfl_xor(s, off);
  if (threadIdx.x == 0) out[0] = (float)(s / (double)(B * N * 2));
}

extern "C" void kernel_launch(void* const* d_in, const int* in_sizes, int n_in,
                              void* d_out, int out_size, void* d_ws, size_t ws_size,
                              hipStream_t stream) {
  const float* pred = (const float*)d_in[0];
  const float* target = (const float*)d_in[1];
  float* out = (float*)d_out;
  double* partial = (double*)d_ws;

  const int B = in_sizes[0] / (N * 2);  // 32

  hipLaunchKernelGGL(hung_kernel, dim3(B), dim3(64), 0, stream, pred, target, partial);
  hipLaunchKernelGGL(reduce_kernel, dim3(1), dim3(64), 0, stream, partial, out, B);
}

// Round 5
// 1704.735 us; speedup vs baseline: 1.4036x; 1.0736x over previous
//
#include <hip/hip_runtime.h>
#include <math.h>

// Hungarian (reference-exact degenerate JV) + MSE.
// Anchored on the round-4 bit-exact kernel. Safety classes preserved:
//   * cross-lane mutable state (pcol, u) lives in LDS with LIVE reads;
//   * registers only for read-only (coords), owner-partitioned (v, uofc RMW
//     targets), or wave-uniform (mark masks, uv0, ui0) state;
//   * NO readlane of mutable registers (the rounds-2/3 failure class).
// Changes vs round 4 (each value-preserving):
//   * u re-indexed by column: uofc[j] = u[pcol[j]]. Valid because p is
//     injective (a row's u is only reachable through its unique column) and
//     a path row's u is read exactly once per outer row, at its row-start
//     value (updates to it land strictly after its scan). Replaces the
//     dependent pcol[j0]->u_lds[i0] 2-hop with two PARALLEL uniform reads,
//     and makes the dual update owner-partitioned (no pcol reads).
//   * used[] replaced by 4 wave-uniform 64-bit lane masks in registers
//     (j1 is uniform; all lanes compute identical masks; no divergent writes).
//   * one real __syncthreads per ROW (augment stores -> next-row reads);
//     in-row cross-lane LDS deps touch disjoint addresses (marked vs
//     unmarked columns), same single-wave in-order-DS pattern round 4 used.
//   * scan expression ((double)c - ui0) - v[k] and first-index argmin
//     (value butterfly + k-major ballots + readlane delta) byte-identical
//     to round 4.

#define N 256

static __device__ __forceinline__ int f2i(float x) { union { float f; int i; } u; u.f = x; return u.i; }
static __device__ __forceinline__ float i2f(int x) { union { float f; int i; } u; u.i = x; return u.f; }
static __device__ __forceinline__ double mkd(int lo, int hi) {
  union { unsigned long long u; double d; } w;
  w.u = (((unsigned long long)(unsigned)hi) << 32) | (unsigned)lo;
  return w.d;
}
static __device__ __forceinline__ int dlo(double d) { union { double d; unsigned long long u; } w; w.d = d; return (int)(unsigned)w.u; }
static __device__ __forceinline__ int dhi(double d) { union { double d; unsigned long long u; } w; w.d = d; return (int)(unsigned)(w.u >> 32); }

__global__ __launch_bounds__(64) void hung_kernel(const float* __restrict__ pred,
                                                  const float* __restrict__ target,
                                                  double* __restrict__ partial) {
  const int b = blockIdx.x;
  const int lane = threadIdx.x;  // single wave per block

  __shared__ float spx[N], spy[N];  // pred coords for final scattered MSE gather
  __shared__ double uofc[N + 1];    // uofc[j] = u[pcol[j]] for assigned columns
  __shared__ int pcol[N + 1];       // column -> assigned row (1-indexed), 0 = free

  // Read-only per-lane data: columns j-1 = lane+64k; rows r-1 = lane+64k.
  float tx[4], ty[4], rpx[4], rpy[4];
  double v[4];  // column duals, owner-lane only

  const float2* pv = (const float2*)pred + (size_t)b * N;
  const float2* tv = (const float2*)target + (size_t)b * N;
#pragma unroll
  for (int k = 0; k < 4; ++k) {
    int idx = lane + 64 * k;
    float2 pp = pv[idx];
    rpx[k] = pp.x; rpy[k] = pp.y;
    spx[idx] = pp.x; spy[idx] = pp.y;
    float2 tt = tv[idx];
    tx[k] = tt.x; ty[k] = tt.y;
    v[k] = 0.0;
  }
#pragma unroll
  for (int k = 0; k < 5; ++k) {
    int j = lane + 64 * k;
    if (j < N + 1) { uofc[j] = 0.0; pcol[j] = 0; }
  }
  __syncthreads();

  for (int i = 1; i <= N; ++i) {
    // wave-uniform mark masks: bit 'lane' of mk_k <=> column 1+lane+64k marked
    unsigned long long ml0 = 0, ml1 = 0, ml2 = 0, ml3 = 0;
    double uv0 = 0.0;  // live u[i] (virtual column 0), wave-uniform
    double ui0 = 0.0;  // row-start u of current i0; row i itself starts at 0
    float pxi, pyi;
    {
      const int rl = (i - 1) & 63, rs = (i - 1) >> 6;
      pxi = i2f(__builtin_amdgcn_readlane(
          rs == 0 ? f2i(rpx[0]) : rs == 1 ? f2i(rpx[1]) : rs == 2 ? f2i(rpx[2]) : f2i(rpx[3]), rl));
      pyi = i2f(__builtin_amdgcn_readlane(
          rs == 0 ? f2i(rpy[0]) : rs == 1 ? f2i(rpy[1]) : rs == 2 ? f2i(rpy[2]) : f2i(rpy[3]), rl));
    }

    int jfin;
    while (true) {
      // ---- scan my free columns: m = ((double)c - ui0) - v[k]
      double m[4];
      double bm = __builtin_huge_val();
#pragma unroll
      for (int k = 0; k < 4; ++k) {
        const unsigned long long ml = k == 0 ? ml0 : k == 1 ? ml1 : k == 2 ? ml2 : ml3;
        double mk = __builtin_huge_val();
        if (!((ml >> lane) & 1)) {
          float dx = pxi - tx[k];
          float dy = pyi - ty[k];
          float c = sqrtf(dx * dx + dy * dy);
          mk = ((double)c - ui0) - v[k];  // reference rounding order
        }
        m[k] = mk;
        if (mk < bm) bm = mk;
      }

      // ---- value-only min butterfly (proven shfl path)
#pragma unroll
      for (int off = 1; off < 64; off <<= 1) {
        double od = __shfl_xor(bm, off);
        if (od < bm) bm = od;
      }

      // ---- argmin j (first-index): k-major ballots == ascending j
      const unsigned long long b0 = __ballot(m[0] == bm);
      const unsigned long long b1 = __ballot(m[1] == bm);
      const unsigned long long b2 = __ballot(m[2] == bm);
      const unsigned long long b3 = __ballot(m[3] == bm);
      const int ks = b0 ? 0 : (b1 ? 1 : (b2 ? 2 : 3));
      const unsigned long long bb = b0 ? b0 : (b1 ? b1 : (b2 ? b2 : b3));
      const int ls = __ffsll(bb) - 1;
      const int j1 = 1 + ls + 64 * ks;

      // ---- issue path-follow reads EARLY (overlap delta + update work).
      // j1 is unmarked => untouched by this row's uofc RMWs => stable.
      const int pcolj = pcol[j1];
      const double uj1 = uofc[j1];

      // ---- delta = m value AT the argmin (bit-exact)
      const int msl = ks == 0 ? dlo(m[0]) : ks == 1 ? dlo(m[1]) : ks == 2 ? dlo(m[2]) : dlo(m[3]);
      const int msh = ks == 0 ? dhi(m[0]) : ks == 1 ? dhi(m[1]) : ks == 2 ? dhi(m[2]) : dhi(m[3]);
      const double delta = mkd(__builtin_amdgcn_readlane(msl, ls),
                               __builtin_amdgcn_readlane(msh, ls));

      // ---- dual update (exact sequential rounding)
      uv0 += delta;  // u[i] via virtual column 0 (marked from step 1)
#pragma unroll
      for (int k = 0; k < 4; ++k) {
        const unsigned long long ml = k == 0 ? ml0 : k == 1 ? ml1 : k == 2 ? ml2 : ml3;
        if ((ml >> lane) & 1) {
          v[k] -= delta;
          uofc[1 + lane + 64 * k] += delta;  // owner-partitioned RMW
        }
      }

      if (pcolj == 0) { jfin = j1; break; }

      // ---- mark j1 (wave-uniform mask update; receives deltas next step on)
      {
        const int cs = (j1 - 1) >> 6;
        const unsigned long long bit = 1ull << ((j1 - 1) & 63);
        if (cs == 0) ml0 |= bit; else if (cs == 1) ml1 |= bit;
        else if (cs == 2) ml2 |= bit; else ml3 |= bit;
      }
      // ---- hop to j1's row: row-start u + coords
      ui0 = uj1;
      {
        const int rl = (pcolj - 1) & 63, rs = (pcolj - 1) >> 6;
        pxi = i2f(__builtin_amdgcn_readlane(
            rs == 0 ? f2i(rpx[0]) : rs == 1 ? f2i(rpx[1]) : rs == 2 ? f2i(rpx[2]) : f2i(rpx[3]), rl));
        pyi = i2f(__builtin_amdgcn_readlane(
            rs == 0 ? f2i(rpy[0]) : rs == 1 ? f2i(rpy[1]) : rs == 2 ? f2i(rpy[2]) : f2i(rpy[3]), rl));
      }
      __builtin_amdgcn_wave_barrier();
    }

    // ---- augment + publish u[i] under its new column (wave-uniform stores)
    pcol[jfin] = i;
    uofc[jfin] = uv0;
    __syncthreads();  // one real barrier per row
  }

  // ---- partial MSE: column j matched to row pcol[j]-1
  double s = 0.0;
#pragma unroll
  for (int k = 0; k < 4; ++k) {
    int j = 1 + lane + 64 * k;
    int r = pcol[j] - 1;
    double dx = (double)spx[r] - (double)tx[k];
    double dy = (double)spy[r] - (double)ty[k];
    s += dx * dx + dy * dy;
  }
#pragma unroll
  for (int off = 1; off < 64; off <<= 1) s += __shfl_xor(s, off);
  if (lane == 0) partial[b] = s;
}

__global__ __launch_bounds__(64) void reduce_kernel(const double* __restrict__ partial,
                                                    float* __restrict__ out, int B) {
  double s = 0.0;
  for (int i = threadIdx.x; i < B; i += 64) s += partial[i];
#pragma unroll
  for (int off = 1; off < 64; off <<= 1) s += __shfl_xor(s, off);
  if (threadIdx.x == 0) out[0] = (float)(s / (double)(B * N * 2));
}

extern "C" void kernel_launch(void* const* d_in, const int* in_sizes, int n_in,
                              void* d_out, int out_size, void* d_ws, size_t ws_size,
                              hipStream_t stream) {
  const float* pred = (const float*)d_in[0];
  const float* target = (const float*)d_in[1];
  float* out = (float*)d_out;
  double* partial = (double*)d_ws;

  const int B = in_sizes[0] / (N * 2);  // 32

  hipLaunchKernelGGL(hung_kernel, dim3(B), dim3(64), 0, stream, pred, target, partial);
  hipLaunchKernelGGL(reduce_kernel, dim3(1), dim3(64), 0, stream, partial, out, B);
}

// Round 7
// 1415.152 us; speedup vs baseline: 1.6908x; 1.2046x over previous
//
#include <hip/hip_runtime.h>
#include <math.h>

// Hungarian (reference-exact degenerate JV) + MSE.
// Anchored on the round-5 bit-exact kernel. Safety classes preserved:
//   * cross-lane mutable state (pcol, uofc, cofc) in LDS with LIVE reads;
//   * registers only for read-only, owner-partitioned, or wave-uniform state;
//   * NO readlane of mutable registers.
// Changes vs round 5 (each value-preserving):
//   * butterfly stages xor1/2/4/8 -> DPP (quad_perm B1, quad_perm 4E,
//     row_half_mirror 0x141, row_mirror 0x140; full row/bank masks; value-only
//     f64 min, strict-<). Within-row exchanges only; stages xor16/xor32 remain
//     on the proven __shfl_xor path. Pure min is order/dup-insensitive, and no
//     -0.0/NaN m-values exist (sqrt>=+0, RN subtraction) so value-min + ballot
//     argmin is bit-exact.  [DPP ctrl codes now LITERAL constants via macro —
//     round 6 failed to compile through a loop variable.]
//   * cofc[j] = pred coords of row pcol[j] (maintained at augment alongside
//     uofc) -> hop coords become a uniform LDS read issued in parallel with
//     pcol[j1]/uofc[j1] instead of readlanes dependent on pcolj.
//   * per-row __syncthreads -> wave_barrier (single-wave block; same-array LDS
//     deps are program-ordered; pattern already validated in-row by r4/r5).

#define N 256

static __device__ __forceinline__ int f2i(float x) { union { float f; int i; } u; u.f = x; return u.i; }
static __device__ __forceinline__ float i2f(int x) { union { float f; int i; } u; u.i = x; return u.f; }
static __device__ __forceinline__ double mkd(int lo, int hi) {
  union { unsigned long long u; double d; } w;
  w.u = (((unsigned long long)(unsigned)hi) << 32) | (unsigned)lo;
  return w.d;
}
static __device__ __forceinline__ int dlo(double d) { union { double d; unsigned long long u; } w; w.d = d; return (int)(unsigned)w.u; }
static __device__ __forceinline__ int dhi(double d) { union { double d; unsigned long long u; } w; w.d = d; return (int)(unsigned)(w.u >> 32); }

// One DPP min stage with LITERAL ctrl (required by the builtin).
#define DPP_MIN_STAGE(CTRL)                                                     \
  {                                                                             \
    int mlo = dlo(bm), mhi = dhi(bm);                                           \
    int slo = __builtin_amdgcn_update_dpp(mlo, mlo, CTRL, 0xF, 0xF, false);     \
    int shi = __builtin_amdgcn_update_dpp(mhi, mhi, CTRL, 0xF, 0xF, false);     \
    double sm = mkd(slo, shi);                                                  \
    if (sm < bm) bm = sm;                                                       \
  }

__global__ __launch_bounds__(64) void hung_kernel(const float* __restrict__ pred,
                                                  const float* __restrict__ target,
                                                  double* __restrict__ partial) {
  const int b = blockIdx.x;
  const int lane = threadIdx.x;  // single wave per block

  __shared__ float spx[N], spy[N];  // pred coords for final scattered MSE gather
  __shared__ double uofc[N + 1];    // uofc[j] = u[pcol[j]] for assigned columns
  __shared__ float2 cofc[N + 1];    // cofc[j] = pred coords of row pcol[j]
  __shared__ int pcol[N + 1];       // column -> assigned row (1-indexed), 0 = free

  // Read-only per-lane data: columns j-1 = lane+64k; rows r-1 = lane+64k.
  float tx[4], ty[4], rpx[4], rpy[4];
  double v[4];  // column duals, owner-lane only

  const float2* pv = (const float2*)pred + (size_t)b * N;
  const float2* tv = (const float2*)target + (size_t)b * N;
#pragma unroll
  for (int k = 0; k < 4; ++k) {
    int idx = lane + 64 * k;
    float2 pp = pv[idx];
    rpx[k] = pp.x; rpy[k] = pp.y;
    spx[idx] = pp.x; spy[idx] = pp.y;
    float2 tt = tv[idx];
    tx[k] = tt.x; ty[k] = tt.y;
    v[k] = 0.0;
  }
#pragma unroll
  for (int k = 0; k < 5; ++k) {
    int j = lane + 64 * k;
    if (j < N + 1) { uofc[j] = 0.0; pcol[j] = 0; cofc[j] = make_float2(0.f, 0.f); }
  }
  __syncthreads();

  for (int i = 1; i <= N; ++i) {
    // wave-uniform mark masks: bit 'lane' of ml_k <=> column 1+lane+64k marked
    unsigned long long ml0 = 0, ml1 = 0, ml2 = 0, ml3 = 0;
    double uv0 = 0.0;  // live u[i] (virtual column 0), wave-uniform
    double ui0 = 0.0;  // row-start u of current i0; row i itself starts at 0
    float pxi, pyi, rix, riy;
    {
      const int rl = (i - 1) & 63, rs = (i - 1) >> 6;
      pxi = i2f(__builtin_amdgcn_readlane(
          rs == 0 ? f2i(rpx[0]) : rs == 1 ? f2i(rpx[1]) : rs == 2 ? f2i(rpx[2]) : f2i(rpx[3]), rl));
      pyi = i2f(__builtin_amdgcn_readlane(
          rs == 0 ? f2i(rpy[0]) : rs == 1 ? f2i(rpy[1]) : rs == 2 ? f2i(rpy[2]) : f2i(rpy[3]), rl));
      rix = pxi; riy = pyi;  // save row-i coords for the augment store
    }

    int jfin;
    while (true) {
      // ---- scan my free columns: m = ((double)c - ui0) - v[k]
      double m[4];
#pragma unroll
      for (int k = 0; k < 4; ++k) {
        const unsigned long long ml = k == 0 ? ml0 : k == 1 ? ml1 : k == 2 ? ml2 : ml3;
        double mk = __builtin_huge_val();
        if (!((ml >> lane) & 1)) {
          float dx = pxi - tx[k];
          float dy = pyi - ty[k];
          float c = sqrtf(dx * dx + dy * dy);
          mk = ((double)c - ui0) - v[k];  // reference rounding order
        }
        m[k] = mk;
      }
      double m01 = m[0] < m[1] ? m[0] : m[1];
      double m23 = m[2] < m[3] ? m[2] : m[3];
      double bm = m01 < m23 ? m01 : m23;

      // ---- wave value-min: 4 DPP within-row stages + 2 shfl cross-row stages
      DPP_MIN_STAGE(0xB1);   // quad_perm [1,0,3,2]  (xor 1)
      DPP_MIN_STAGE(0x4E);   // quad_perm [2,3,0,1]  (xor 2)
      DPP_MIN_STAGE(0x141);  // row_half_mirror      (xor 4)
      DPP_MIN_STAGE(0x140);  // row_mirror           (xor 8)
#pragma unroll
      for (int off = 16; off < 64; off <<= 1) {
        double od = __shfl_xor(bm, off);
        if (od < bm) bm = od;
      }

      // ---- argmin j (first-index): k-major ballots == ascending j
      const unsigned long long b0 = __ballot(m[0] == bm);
      const unsigned long long b1 = __ballot(m[1] == bm);
      const unsigned long long b2 = __ballot(m[2] == bm);
      const unsigned long long b3 = __ballot(m[3] == bm);
      const int ks = b0 ? 0 : (b1 ? 1 : (b2 ? 2 : 3));
      const unsigned long long bb = b0 ? b0 : (b1 ? b1 : (b2 ? b2 : b3));
      const int ls = __ffsll(bb) - 1;
      const int j1 = 1 + ls + 64 * ks;

      // ---- path-follow reads, all PARALLEL uniform LDS loads.
      // j1 is unmarked => untouched by this row's uofc RMWs => stable.
      const int pcolj = pcol[j1];
      const double uj1 = uofc[j1];
      const float2 cj1 = cofc[j1];

      // ---- delta = m value AT the argmin (bit-exact; off critical path)
      const int msl = ks == 0 ? dlo(m[0]) : ks == 1 ? dlo(m[1]) : ks == 2 ? dlo(m[2]) : dlo(m[3]);
      const int msh = ks == 0 ? dhi(m[0]) : ks == 1 ? dhi(m[1]) : ks == 2 ? dhi(m[2]) : dhi(m[3]);
      const double delta = mkd(__builtin_amdgcn_readlane(msl, ls),
                               __builtin_amdgcn_readlane(msh, ls));

      // ---- dual update (exact sequential rounding; marked columns only,
      //      which are excluded from scans => off the critical path)
      uv0 += delta;  // u[i] via virtual column 0 (marked from step 1)
#pragma unroll
      for (int k = 0; k < 4; ++k) {
        const unsigned long long ml = k == 0 ? ml0 : k == 1 ? ml1 : k == 2 ? ml2 : ml3;
        if ((ml >> lane) & 1) {
          v[k] -= delta;
          uofc[1 + lane + 64 * k] += delta;  // owner-partitioned RMW
        }
      }

      if (pcolj == 0) { jfin = j1; break; }

      // ---- mark j1 (wave-uniform mask update; receives deltas next step on)
      {
        const int cs = (j1 - 1) >> 6;
        const unsigned long long bit = 1ull << ((j1 - 1) & 63);
        if (cs == 0) ml0 |= bit; else if (cs == 1) ml1 |= bit;
        else if (cs == 2) ml2 |= bit; else ml3 |= bit;
      }
      // ---- hop to j1's row: row-start u + coords (from the parallel reads)
      ui0 = uj1;
      pxi = cj1.x; pyi = cj1.y;
      __builtin_amdgcn_wave_barrier();
    }

    // ---- augment + publish row i's state under its new column (uniform stores)
    pcol[jfin] = i;
    uofc[jfin] = uv0;
    cofc[jfin] = make_float2(rix, riy);
    __builtin_amdgcn_wave_barrier();  // single-wave block: program-order LDS
  }

  __syncthreads();
  // ---- partial MSE: column j matched to row pcol[j]-1
  double s = 0.0;
#pragma unroll
  for (int k = 0; k < 4; ++k) {
    int j = 1 + lane + 64 * k;
    int r = pcol[j] - 1;
    double dx = (double)spx[r] - (double)tx[k];
    double dy = (double)spy[r] - (double)ty[k];
    s += dx * dx + dy * dy;
  }
#pragma unroll
  for (int off = 1; off < 64; off <<= 1) s += __shfl_xor(s, off);
  if (lane == 0) partial[b] = s;
}

__global__ __launch_bounds__(64) void reduce_kernel(const double* __restrict__ partial,
                                                    float* __restrict__ out, int B) {
  double s = 0.0;
  for (int i = threadIdx.x; i < B; i += 64) s += partial[i];
#pragma unroll
  for (int off = 1; off < 64; off <<= 1) s += __shfl_xor(s, off);
  if (threadIdx.x == 0) out[0] = (float)(s / (double)(B * N * 2));
}

extern "C" void kernel_launch(void* const* d_in, const int* in_sizes, int n_in,
                              void* d_out, int out_size, void* d_ws, size_t ws_size,
                              hipStream_t stream) {
  const float* pred = (const float*)d_in[0];
  const float* target = (const float*)d_in[1];
  float* out = (float*)d_out;
  double* partial = (double*)d_ws;

  const int B = in_sizes[0] / (N * 2);  // 32

  hipLaunchKernelGGL(hung_kernel, dim3(B), dim3(64), 0, stream, pred, target, partial);
  hipLaunchKernelGGL(reduce_kernel, dim3(1), dim3(64), 0, stream, partial, out, B);
}

// Round 8
// 1239.944 us; speedup vs baseline: 1.9298x; 1.1413x over previous
//
#include <hip/hip_runtime.h>
#include <math.h>

// Hungarian (reference-exact degenerate JV) + MSE.
// Anchored on the round-7 bit-exact kernel. Safety classes preserved:
//   * cross-lane mutable state (pcol, uofc, cofc) in LDS with LIVE reads;
//   * registers only for read-only, owner-partitioned, or wave-uniform state;
//   * NO readlane of mutable registers (readlane of the just-computed
//     reduction temporaries bm is fine: value produced this step).
// Changes vs round 7 (each value-preserving):
//   * butterfly tail xor16/xor32 (ds_bpermute) -> DPP row_bcast15 (0x142,
//     row_mask 0xA) + row_bcast31 (0x143, row_mask 0xC), value-only f64 min;
//     global min lands in lane 63, broadcast via 2x readlane into SGPRs.
//   * delta = gmin DIRECTLY: min is bitwise one of the m values (no -0.0: RN
//     subtraction yields +0 on exact cancellation; sqrt >= +0; no NaN), so
//     the ballot-dependent readlane delta extraction is deleted.
//   * ballots now only produce argmin j1 (first-index, k-major order).

#define N 256

static __device__ __forceinline__ int f2i(float x) { union { float f; int i; } u; u.f = x; return u.i; }
static __device__ __forceinline__ float i2f(int x) { union { float f; int i; } u; u.i = x; return u.f; }
static __device__ __forceinline__ double mkd(int lo, int hi) {
  union { unsigned long long u; double d; } w;
  w.u = (((unsigned long long)(unsigned)hi) << 32) | (unsigned)lo;
  return w.d;
}
static __device__ __forceinline__ int dlo(double d) { union { double d; unsigned long long u; } w; w.d = d; return (int)(unsigned)w.u; }
static __device__ __forceinline__ int dhi(double d) { union { double d; unsigned long long u; } w; w.d = d; return (int)(unsigned)(w.u >> 32); }

// One DPP min stage with LITERAL ctrl/row_mask (required by the builtin).
// Masked-out lanes keep old (= their own bm) since old operand is bm.
#define DPP_MIN_STAGE(CTRL, RMASK)                                              \
  {                                                                             \
    int mlo = dlo(bm), mhi = dhi(bm);                                           \
    int slo = __builtin_amdgcn_update_dpp(mlo, mlo, CTRL, RMASK, 0xF, false);   \
    int shi = __builtin_amdgcn_update_dpp(mhi, mhi, CTRL, RMASK, 0xF, false);   \
    double sm = mkd(slo, shi);                                                  \
    if (sm < bm) bm = sm;                                                       \
  }

__global__ __launch_bounds__(64) void hung_kernel(const float* __restrict__ pred,
                                                  const float* __restrict__ target,
                                                  double* __restrict__ partial) {
  const int b = blockIdx.x;
  const int lane = threadIdx.x;  // single wave per block

  __shared__ float spx[N], spy[N];  // pred coords for final scattered MSE gather
  __shared__ double uofc[N + 1];    // uofc[j] = u[pcol[j]] for assigned columns
  __shared__ float2 cofc[N + 1];    // cofc[j] = pred coords of row pcol[j]
  __shared__ int pcol[N + 1];       // column -> assigned row (1-indexed), 0 = free

  // Read-only per-lane data: columns j-1 = lane+64k; rows r-1 = lane+64k.
  float tx[4], ty[4], rpx[4], rpy[4];
  double v[4];  // column duals, owner-lane only

  const float2* pv = (const float2*)pred + (size_t)b * N;
  const float2* tv = (const float2*)target + (size_t)b * N;
#pragma unroll
  for (int k = 0; k < 4; ++k) {
    int idx = lane + 64 * k;
    float2 pp = pv[idx];
    rpx[k] = pp.x; rpy[k] = pp.y;
    spx[idx] = pp.x; spy[idx] = pp.y;
    float2 tt = tv[idx];
    tx[k] = tt.x; ty[k] = tt.y;
    v[k] = 0.0;
  }
#pragma unroll
  for (int k = 0; k < 5; ++k) {
    int j = lane + 64 * k;
    if (j < N + 1) { uofc[j] = 0.0; pcol[j] = 0; cofc[j] = make_float2(0.f, 0.f); }
  }
  __syncthreads();

  for (int i = 1; i <= N; ++i) {
    // wave-uniform mark masks: bit 'lane' of ml_k <=> column 1+lane+64k marked
    unsigned long long ml0 = 0, ml1 = 0, ml2 = 0, ml3 = 0;
    double uv0 = 0.0;  // live u[i] (virtual column 0), wave-uniform
    double ui0 = 0.0;  // row-start u of current i0; row i itself starts at 0
    float pxi, pyi, rix, riy;
    {
      const int rl = (i - 1) & 63, rs = (i - 1) >> 6;
      pxi = i2f(__builtin_amdgcn_readlane(
          rs == 0 ? f2i(rpx[0]) : rs == 1 ? f2i(rpx[1]) : rs == 2 ? f2i(rpx[2]) : f2i(rpx[3]), rl));
      pyi = i2f(__builtin_amdgcn_readlane(
          rs == 0 ? f2i(rpy[0]) : rs == 1 ? f2i(rpy[1]) : rs == 2 ? f2i(rpy[2]) : f2i(rpy[3]), rl));
      rix = pxi; riy = pyi;  // save row-i coords for the augment store
    }

    int jfin;
    while (true) {
      // ---- scan my free columns: m = ((double)c - ui0) - v[k]
      double m[4];
#pragma unroll
      for (int k = 0; k < 4; ++k) {
        const unsigned long long ml = k == 0 ? ml0 : k == 1 ? ml1 : k == 2 ? ml2 : ml3;
        double mk = __builtin_huge_val();
        if (!((ml >> lane) & 1)) {
          float dx = pxi - tx[k];
          float dy = pyi - ty[k];
          float c = sqrtf(dx * dx + dy * dy);
          mk = ((double)c - ui0) - v[k];  // reference rounding order
        }
        m[k] = mk;
      }
      double m01 = m[0] < m[1] ? m[0] : m[1];
      double m23 = m[2] < m[3] ? m[2] : m[3];
      double bm = m01 < m23 ? m01 : m23;

      // ---- wave value-min entirely in DPP: 4 butterfly stages + 2 bcast
      DPP_MIN_STAGE(0xB1, 0xF);   // quad_perm [1,0,3,2]  (xor 1)
      DPP_MIN_STAGE(0x4E, 0xF);   // quad_perm [2,3,0,1]  (xor 2)
      DPP_MIN_STAGE(0x141, 0xF);  // row_half_mirror      (xor 4)
      DPP_MIN_STAGE(0x140, 0xF);  // row_mirror           (xor 8)
      DPP_MIN_STAGE(0x142, 0xA);  // row_bcast15 -> rows 1,3
      DPP_MIN_STAGE(0x143, 0xC);  // row_bcast31 -> rows 2,3
      // global min now in lane 63; broadcast via SGPRs. delta == gmin bitwise.
      const double delta = mkd(__builtin_amdgcn_readlane(dlo(bm), 63),
                               __builtin_amdgcn_readlane(dhi(bm), 63));

      // ---- argmin j (first-index): k-major ballots == ascending j
      const unsigned long long b0 = __ballot(m[0] == delta);
      const unsigned long long b1 = __ballot(m[1] == delta);
      const unsigned long long b2 = __ballot(m[2] == delta);
      const unsigned long long b3 = __ballot(m[3] == delta);
      const int ks = b0 ? 0 : (b1 ? 1 : (b2 ? 2 : 3));
      const unsigned long long bb = b0 ? b0 : (b1 ? b1 : (b2 ? b2 : b3));
      const int ls = __ffsll(bb) - 1;
      const int j1 = 1 + ls + 64 * ks;

      // ---- path-follow reads, all PARALLEL uniform LDS loads.
      // j1 is unmarked => untouched by this row's uofc RMWs => stable.
      const int pcolj = pcol[j1];
      const double uj1 = uofc[j1];
      const float2 cj1 = cofc[j1];

      // ---- dual update (exact sequential rounding; marked columns only,
      //      which are excluded from scans => off the critical path)
      uv0 += delta;  // u[i] via virtual column 0 (marked from step 1)
#pragma unroll
      for (int k = 0; k < 4; ++k) {
        const unsigned long long ml = k == 0 ? ml0 : k == 1 ? ml1 : k == 2 ? ml2 : ml3;
        if ((ml >> lane) & 1) {
          v[k] -= delta;
          uofc[1 + lane + 64 * k] += delta;  // owner-partitioned RMW
        }
      }

      if (pcolj == 0) { jfin = j1; break; }

      // ---- mark j1 (wave-uniform mask update; receives deltas next step on)
      {
        const int cs = (j1 - 1) >> 6;
        const unsigned long long bit = 1ull << ((j1 - 1) & 63);
        if (cs == 0) ml0 |= bit; else if (cs == 1) ml1 |= bit;
        else if (cs == 2) ml2 |= bit; else ml3 |= bit;
      }
      // ---- hop to j1's row: row-start u + coords (from the parallel reads)
      ui0 = uj1;
      pxi = cj1.x; pyi = cj1.y;
      __builtin_amdgcn_wave_barrier();
    }

    // ---- augment + publish row i's state under its new column (uniform stores)
    pcol[jfin] = i;
    uofc[jfin] = uv0;
    cofc[jfin] = make_float2(rix, riy);
    __builtin_amdgcn_wave_barrier();  // single-wave block: program-order LDS
  }

  __syncthreads();
  // ---- partial MSE: column j matched to row pcol[j]-1
  double s = 0.0;
#pragma unroll
  for (int k = 0; k < 4; ++k) {
    int j = 1 + lane + 64 * k;
    int r = pcol[j] - 1;
    double dx = (double)spx[r] - (double)tx[k];
    double dy = (double)spy[r] - (double)ty[k];
    s += dx * dx + dy * dy;
  }
#pragma unroll
  for (int off = 1; off < 64; off <<= 1) s += __shfl_xor(s, off);
  if (lane == 0) partial[b] = s;
}

__global__ __launch_bounds__(64) void reduce_kernel(const double* __restrict__ partial,
                                                    float* __restrict__ out, int B) {
  double s = 0.0;
  for (int i = threadIdx.x; i < B; i += 64) s += partial[i];
#pragma unroll
  for (int off = 1; off < 64; off <<= 1) s += __shfl_xor(s, off);
  if (threadIdx.x == 0) out[0] = (float)(s / (double)(B * N * 2));
}

extern "C" void kernel_launch(void* const* d_in, const int* in_sizes, int n_in,
                              void* d_out, int out_size, void* d_ws, size_t ws_size,
                              hipStream_t stream) {
  const float* pred = (const float*)d_in[0];
  const float* target = (const float*)d_in[1];
  float* out = (float*)d_out;
  double* partial = (double*)d_ws;

  const int B = in_sizes[0] / (N * 2);  // 32

  hipLaunchKernelGGL(hung_kernel, dim3(B), dim3(64), 0, stream, pred, target, partial);
  hipLaunchKernelGGL(reduce_kernel, dim3(1), dim3(64), 0, stream, partial, out, B);
}

// Round 10
// 1141.016 us; speedup vs baseline: 2.0971x; 1.0867x over previous
//
#include <hip/hip_runtime.h>
#include <math.h>

// Hungarian (reference-exact degenerate JV) + MSE.
// Anchored on the round-8 bit-exact kernel (1240us). Changes vs r8:
//   * fmin for all f64 mins (v_min_f64, 1 instr): bit-exact for NaN-free,
//     -0-free values (sqrt>=+0; RN cancellation gives +0).
//   * uofc+cofc packed into one 16B LDS struct {u, cx, cy} -> hop reads are
//     ONE ds_read_b128 (+ parallel pcol b32). spx/spy deleted (final MSE
//     reads coords from the packed struct).
// HARD RULE (r2/r3/r9 all failed on it; r9 hung): cross-lane MUTABLE state
// (pcol, u, coords-of-column) must live in LDS with live reads. readlane is
// safe ONLY for read-only data or same-step temporaries (DPP bm, delta).
// Everything else (masks-in-SGPR marks, owner-partitioned v[] in registers,
// wave-uniform augment stores, DPP value-min + k-major ballots) is r8-proven.

#define N 256

static __device__ __forceinline__ int f2i(float x) { union { float f; int i; } u; u.f = x; return u.i; }
static __device__ __forceinline__ float i2f(int x) { union { float f; int i; } u; u.i = x; return u.f; }
static __device__ __forceinline__ double mkd(int lo, int hi) {
  union { unsigned long long u; double d; } w;
  w.u = (((unsigned long long)(unsigned)hi) << 32) | (unsigned)lo;
  return w.d;
}
static __device__ __forceinline__ int dlo(double d) { union { double d; unsigned long long u; } w; w.d = d; return (int)(unsigned)w.u; }
static __device__ __forceinline__ int dhi(double d) { union { double d; unsigned long long u; } w; w.d = d; return (int)(unsigned)(w.u >> 32); }

// One DPP f64-min stage with LITERAL ctrl/row_mask. Masked-out lanes keep
// their own bm (old operand). fmin == strict-< select for NaN-free values.
#define DPP_MIN_STAGE(CTRL, RMASK)                                              \
  {                                                                             \
    int mlo = dlo(bm), mhi = dhi(bm);                                           \
    int slo = __builtin_amdgcn_update_dpp(mlo, mlo, CTRL, RMASK, 0xF, false);   \
    int shi = __builtin_amdgcn_update_dpp(mhi, mhi, CTRL, RMASK, 0xF, false);   \
    bm = fmin(bm, mkd(slo, shi));                                               \
  }

struct alignas(16) UC { double u; float cx, cy; };  // 16B: one ds_read_b128

__global__ __launch_bounds__(64) void hung_kernel(const float* __restrict__ pred,
                                                  const float* __restrict__ target,
                                                  double* __restrict__ partial) {
  const int b = blockIdx.x;
  const int lane = threadIdx.x;  // single wave per block

  __shared__ UC ucofc[N + 1];   // per column: {u of its row, row pred coords}
  __shared__ int pcol[N + 1];   // column -> assigned row (1-indexed), 0 = free

  // Read-only per-lane data: columns j-1 = lane+64k; rows r-1 = lane+64k.
  float tx[4], ty[4], rpx[4], rpy[4];
  double v[4];  // column duals, owner-lane only

  const float2* pv = (const float2*)pred + (size_t)b * N;
  const float2* tv = (const float2*)target + (size_t)b * N;
#pragma unroll
  for (int k = 0; k < 4; ++k) {
    int idx = lane + 64 * k;
    float2 pp = pv[idx];
    rpx[k] = pp.x; rpy[k] = pp.y;
    float2 tt = tv[idx];
    tx[k] = tt.x; ty[k] = tt.y;
    v[k] = 0.0;
  }
#pragma unroll
  for (int k = 0; k < 5; ++k) {
    int j = lane + 64 * k;
    if (j < N + 1) { ucofc[j].u = 0.0; ucofc[j].cx = 0.f; ucofc[j].cy = 0.f; pcol[j] = 0; }
  }
  __syncthreads();

  for (int i = 1; i <= N; ++i) {
    // wave-uniform mark masks: bit 'lane' of ml_k <=> column 1+lane+64k marked
    unsigned long long ml0 = 0, ml1 = 0, ml2 = 0, ml3 = 0;
    double uv0 = 0.0;  // live u[i] (virtual column 0), wave-uniform
    double ui0 = 0.0;  // row-start u of current i0; row i itself starts at 0
    float pxi, pyi, rix, riy;
    {
      const int rl = (i - 1) & 63, rs = (i - 1) >> 6;
      pxi = i2f(__builtin_amdgcn_readlane(
          rs == 0 ? f2i(rpx[0]) : rs == 1 ? f2i(rpx[1]) : rs == 2 ? f2i(rpx[2]) : f2i(rpx[3]), rl));
      pyi = i2f(__builtin_amdgcn_readlane(
          rs == 0 ? f2i(rpy[0]) : rs == 1 ? f2i(rpy[1]) : rs == 2 ? f2i(rpy[2]) : f2i(rpy[3]), rl));
      rix = pxi; riy = pyi;  // saved for the augment store
    }

    int jfin;
    while (true) {
      // ---- scan my free columns: m = ((double)c - ui0) - v[k]
      double m[4];
#pragma unroll
      for (int k = 0; k < 4; ++k) {
        const unsigned long long ml = k == 0 ? ml0 : k == 1 ? ml1 : k == 2 ? ml2 : ml3;
        double mk = __builtin_huge_val();
        if (!((ml >> lane) & 1)) {
          float dx = pxi - tx[k];
          float dy = pyi - ty[k];
          float c = sqrtf(dx * dx + dy * dy);
          mk = ((double)c - ui0) - v[k];  // reference rounding order
        }
        m[k] = mk;
      }
      double bm = fmin(fmin(m[0], m[1]), fmin(m[2], m[3]));

      // ---- wave value-min entirely in DPP: 4 butterfly stages + 2 bcast
      DPP_MIN_STAGE(0xB1, 0xF);   // quad_perm [1,0,3,2]  (xor 1)
      DPP_MIN_STAGE(0x4E, 0xF);   // quad_perm [2,3,0,1]  (xor 2)
      DPP_MIN_STAGE(0x141, 0xF);  // row_half_mirror      (xor 4)
      DPP_MIN_STAGE(0x140, 0xF);  // row_mirror           (xor 8)
      DPP_MIN_STAGE(0x142, 0xA);  // row_bcast15 -> rows 1,3
      DPP_MIN_STAGE(0x143, 0xC);  // row_bcast31 -> rows 2,3
      // global min in lane 63; broadcast via SGPRs. delta == gmin bitwise.
      const double delta = mkd(__builtin_amdgcn_readlane(dlo(bm), 63),
                               __builtin_amdgcn_readlane(dhi(bm), 63));

      // ---- argmin j (first-index): k-major ballots == ascending j
      const unsigned long long b0 = __ballot(m[0] == delta);
      const unsigned long long b1 = __ballot(m[1] == delta);
      const unsigned long long b2 = __ballot(m[2] == delta);
      const unsigned long long b3 = __ballot(m[3] == delta);
      const int ks = b0 ? 0 : (b1 ? 1 : (b2 ? 2 : 3));
      const unsigned long long bb = b0 ? b0 : (b1 ? b1 : (b2 ? b2 : b3));
      const int ls = __ffsll(bb) - 1;
      const int j1 = 1 + ls + 64 * ks;

      // ---- path-follow reads: ONE b128 (u+coords) + parallel b32 (pcol).
      // j1 is unmarked => untouched by this row's ucofc RMWs => stable.
      const UC hop = ucofc[j1];
      const int pcolj = pcol[j1];

      // ---- dual update (exact sequential rounding; marked columns only,
      //      which are excluded from scans => off the critical path)
      uv0 += delta;  // u[i] via virtual column 0 (marked from step 1)
#pragma unroll
      for (int k = 0; k < 4; ++k) {
        const unsigned long long ml = k == 0 ? ml0 : k == 1 ? ml1 : k == 2 ? ml2 : ml3;
        if ((ml >> lane) & 1) {
          v[k] -= delta;
          ucofc[1 + lane + 64 * k].u += delta;  // owner-partitioned RMW
        }
      }

      if (pcolj == 0) { jfin = j1; break; }

      // ---- mark j1 (wave-uniform mask update; receives deltas next step on)
      {
        const unsigned long long bit = 1ull << ls;
        if (ks == 0) ml0 |= bit; else if (ks == 1) ml1 |= bit;
        else if (ks == 2) ml2 |= bit; else ml3 |= bit;
      }
      // ---- hop to j1's row: row-start u + coords (from the b128 read)
      ui0 = hop.u;
      pxi = hop.cx; pyi = hop.cy;
      __builtin_amdgcn_wave_barrier();
    }

    // ---- augment + publish row i's state under its new column (uniform stores)
    pcol[jfin] = i;
    UC nu; nu.u = uv0; nu.cx = rix; nu.cy = riy;
    ucofc[jfin] = nu;
    __builtin_amdgcn_wave_barrier();  // single-wave block: program-order LDS
  }

  __syncthreads();
  // ---- partial MSE: column j matched to row pcol[j]; its coords are in ucofc
  double s = 0.0;
#pragma unroll
  for (int k = 0; k < 4; ++k) {
    int j = 1 + lane + 64 * k;
    UC t = ucofc[j];
    double dx = (double)t.cx - (double)tx[k];
    double dy = (double)t.cy - (double)ty[k];
    s += dx * dx + dy * dy;
  }
#pragma unroll
  for (int off = 1; off < 64; off <<= 1) s += __shfl_xor(s, off);
  if (lane == 0) partial[b] = s;
}

__global__ __launch_bounds__(64) void reduce_kernel(const double* __restrict__ partial,
                                                    float* __restrict__ out, int B) {
  double s = 0.0;
  for (int i = threadIdx.x; i < B; i += 64) s += partial[i];
#pragma unroll
  for (int off = 1; off < 64; off <<= 1) s += __shfl_xor(s, off);
  if (threadIdx.x == 0) out[0] = (float)(s / (double)(B * N * 2));
}

extern "C" void kernel_launch(void* const* d_in, const int* in_sizes, int n_in,
                              void* d_out, int out_size, void* d_ws, size_t ws_size,
                              hipStream_t stream) {
  const float* pred = (const float*)d_in[0];
  const float* target = (const float*)d_in[1];
  float* out = (float*)d_out;
  double* partial = (double*)d_ws;

  const int B = in_sizes[0] / (N * 2);  // 32

  hipLaunchKernelGGL(hung_kernel, dim3(B), dim3(64), 0, stream, pred, target, partial);
  hipLaunchKernelGGL(reduce_kernel, dim3(1), dim3(64), 0, stream, partial, out, B);
}